// Round 5
// baseline (504.772 us; speedup 1.0000x reference)
//
#include <hip/hip_runtime.h>

#define N_NODES 100000
#define N_EDGES 800000
#define D 128

typedef __attribute__((ext_vector_type(8))) short short8;
typedef __attribute__((ext_vector_type(4))) float f32x4;

__device__ inline unsigned short f2bf(float f) {
  unsigned u = __float_as_uint(f);
  unsigned r = (u + 0x7fffu + ((u >> 16) & 1u)) >> 16;
  return (unsigned short)r;
}
__device__ inline void bfma8(float* acc, const uint4 v, float d) {
  acc[0] = fmaf(__uint_as_float(v.x << 16), d, acc[0]);
  acc[1] = fmaf(__uint_as_float(v.x & 0xffff0000u), d, acc[1]);
  acc[2] = fmaf(__uint_as_float(v.y << 16), d, acc[2]);
  acc[3] = fmaf(__uint_as_float(v.y & 0xffff0000u), d, acc[3]);
  acc[4] = fmaf(__uint_as_float(v.z << 16), d, acc[4]);
  acc[5] = fmaf(__uint_as_float(v.z & 0xffff0000u), d, acc[5]);
  acc[6] = fmaf(__uint_as_float(v.w << 16), d, acc[6]);
  acc[7] = fmaf(__uint_as_float(v.w & 0xffff0000u), d, acc[7]);
}
__device__ inline void unpack8(float* o, const uint4 v) {
  o[0] = __uint_as_float(v.x << 16); o[1] = __uint_as_float(v.x & 0xffff0000u);
  o[2] = __uint_as_float(v.y << 16); o[3] = __uint_as_float(v.y & 0xffff0000u);
  o[4] = __uint_as_float(v.z << 16); o[5] = __uint_as_float(v.z & 0xffff0000u);
  o[6] = __uint_as_float(v.w << 16); o[7] = __uint_as_float(v.w & 0xffff0000u);
}
__device__ inline uint4 pack8(const float* v) {
  uint4 r;
  r.x = (unsigned)f2bf(v[0]) | ((unsigned)f2bf(v[1]) << 16);
  r.y = (unsigned)f2bf(v[2]) | ((unsigned)f2bf(v[3]) << 16);
  r.z = (unsigned)f2bf(v[4]) | ((unsigned)f2bf(v[5]) << 16);
  r.w = (unsigned)f2bf(v[6]) | ((unsigned)f2bf(v[7]) << 16);
  return r;
}

// ---------------- degree count (int atomics) ----------------
__global__ void k_deg(const int* __restrict__ dst, int* __restrict__ degs) {
  int e = blockIdx.x * 256 + threadIdx.x;
  if (e < N_EDGES) atomicAdd(&degs[dst[e]], 1);
}

// ---------------- 2-level exclusive scan over degrees ----------------
__global__ void k_scan1(const int* __restrict__ degs, int* __restrict__ offs,
                        int* __restrict__ aux) {
  __shared__ int s[256];
  int tid = threadIdx.x;
  int i = blockIdx.x * 256 + tid;
  int v = (i < N_NODES) ? degs[i] : 0;
  int sum = v;
  s[tid] = sum; __syncthreads();
  for (int off = 1; off < 256; off <<= 1) {
    int t = (tid >= off) ? s[tid - off] : 0;
    __syncthreads();
    sum += t; s[tid] = sum;
    __syncthreads();
  }
  if (i < N_NODES) offs[i] = sum - v;
  if (tid == 255) aux[blockIdx.x] = sum;
}

__global__ void k_scan2(const int* __restrict__ aux, int* __restrict__ aux2, int nblk) {
  __shared__ int s[512];
  int tid = threadIdx.x;
  int v = (tid < nblk) ? aux[tid] : 0;
  int sum = v;
  s[tid] = sum; __syncthreads();
  for (int off = 1; off < 512; off <<= 1) {
    int t = (tid >= off) ? s[tid - off] : 0;
    __syncthreads();
    sum += t; s[tid] = sum;
    __syncthreads();
  }
  aux2[tid] = sum - v;
}

__global__ void k_scan3(int* __restrict__ offs, const int* __restrict__ aux2,
                        const int* __restrict__ degs, float* __restrict__ dinv) {
  int i = blockIdx.x * 256 + threadIdx.x;
  if (i < N_NODES) {
    offs[i] += aux2[blockIdx.x];
    dinv[i] = rsqrtf(fmaxf((float)degs[i], 1.0f));
  }
}

// ---------------- CSR fill (counting sort by dst) ----------------
__global__ void k_fill(const int* __restrict__ src, const int* __restrict__ dst,
                       const int* __restrict__ offs, int* __restrict__ cursor,
                       int* __restrict__ csr) {
  int e = blockIdx.x * 256 + threadIdx.x;
  if (e < N_EDGES) {
    int d = dst[e];
    int pos = offs[d] + atomicAdd(&cursor[d], 1);
    csr[pos] = src[e];
  }
}

// ---------------- per-node MLP -> prob -> xk(bf16) ----------------
__global__ __launch_bounds__(256, 2)
void k_mlp(const float* __restrict__ x, const float* __restrict__ w1,
           const float* __restrict__ w2, const float* __restrict__ b1,
           const float* __restrict__ b2, const float* __restrict__ emb,
           const float* __restrict__ alpha_p, unsigned short* __restrict__ xk_bf) {
  __shared__ __align__(16) float xsT[128 * 68];
  __shared__ __align__(16) float w1sT[32 * 128];
  __shared__ float zbuf[64];
  __shared__ float pbuf[64];

  int tid = threadIdx.x;
  int lane = tid & 63;
  int wave = tid >> 6;
  int n0 = blockIdx.x * 64;

  {
    int n = lane;
    int gn = n0 + n;
    const float4* xr = (const float4*)(x + (size_t)gn * 128 + wave * 32);
    #pragma unroll
    for (int i = 0; i < 8; i++) {
      float4 v = make_float4(0.f, 0.f, 0.f, 0.f);
      if (gn < N_NODES) v = xr[i];
      int k = wave * 32 + i * 4;
      xsT[(k + 0) * 68 + n] = v.x;
      xsT[(k + 1) * 68 + n] = v.y;
      xsT[(k + 2) * 68 + n] = v.z;
      xsT[(k + 3) * 68 + n] = v.w;
    }
  }

  int d8 = tid & 15;
  int n4 = tid >> 4;
  float acc[4][8];
  #pragma unroll
  for (int a = 0; a < 4; a++)
    #pragma unroll
    for (int c = 0; c < 8; c++) acc[a][c] = 0.f;

  for (int p = 0; p < 4; p++) {
    __syncthreads();
    {
      int j = tid >> 1;
      int kg0 = (tid & 1) * 4;
      const float4* wr = (const float4*)(w1 + j * 128 + p * 32);
      #pragma unroll
      for (int c = 0; c < 4; c++) {
        float4 v = wr[kg0 + c];
        int k = (kg0 + c) * 4;
        w1sT[(k + 0) * 128 + j] = v.x;
        w1sT[(k + 1) * 128 + j] = v.y;
        w1sT[(k + 2) * 128 + j] = v.z;
        w1sT[(k + 3) * 128 + j] = v.w;
      }
    }
    __syncthreads();

    for (int kk = 0; kk < 32; kk += 4) {
      float wq[4][8];
      float4 f[4];
      #pragma unroll
      for (int q = 0; q < 4; q++) {
        const float4* wr = (const float4*)(w1sT + (kk + q) * 128 + d8 * 8);
        float4 a = wr[0], b = wr[1];
        wq[q][0] = a.x; wq[q][1] = a.y; wq[q][2] = a.z; wq[q][3] = a.w;
        wq[q][4] = b.x; wq[q][5] = b.y; wq[q][6] = b.z; wq[q][7] = b.w;
        f[q] = *(const float4*)(xsT + (p * 32 + kk + q) * 68 + n4 * 4);
      }
      #pragma unroll
      for (int q = 0; q < 4; q++) {
        #pragma unroll
        for (int c = 0; c < 8; c++) {
          acc[0][c] += f[q].x * wq[q][c];
          acc[1][c] += f[q].y * wq[q][c];
          acc[2][c] += f[q].z * wq[q][c];
          acc[3][c] += f[q].w * wq[q][c];
        }
      }
    }
  }

  {
    int j0 = d8 * 8;
    float bb[8], wd[8];
    #pragma unroll
    for (int c = 0; c < 8; c++) {
      bb[c] = b1[j0 + c];
      wd[c] = w2[128 + j0 + c] - w2[j0 + c];
    }
    #pragma unroll
    for (int a = 0; a < 4; a++) {
      float s = 0.f;
      #pragma unroll
      for (int c = 0; c < 8; c++) {
        float h = fmaxf(acc[a][c] + bb[c], 0.f);
        s += h * wd[c];
      }
      s += __shfl_down(s, 8);
      s += __shfl_down(s, 4);
      s += __shfl_down(s, 2);
      s += __shfl_down(s, 1);
      if (d8 == 0) zbuf[n4 * 4 + a] = s;
    }
  }
  __syncthreads();
  if (tid < 64) {
    float db2 = b2[1] - b2[0];
    float z = zbuf[tid] + db2;
    pbuf[tid] = 1.f / (1.f + expf(-z));
  }
  __syncthreads();

  {
    float al = alpha_p[0];
    int d4 = tid & 31;
    const float4 e0 = ((const float4*)emb)[d4];
    const float4 e1 = ((const float4*)(emb + 128))[d4];
    #pragma unroll
    for (int i = 0; i < 8; i++) {
      int n = i * 8 + (tid >> 5);
      int gn = n0 + n;
      if (gn >= N_NODES) continue;
      float p = pbuf[n];
      float c0 = al * (1.f - p), c1 = al * p;
      float4 xv = ((const float4*)x)[(size_t)gn * 32 + d4];
      float o0 = xv.x + c0 * e0.x + c1 * e1.x;
      float o1 = xv.y + c0 * e0.y + c1 * e1.y;
      float o2 = xv.z + c0 * e0.z + c1 * e1.z;
      float o3 = xv.w + c0 * e0.w + c1 * e1.w;
      ushort4 ov = make_ushort4(f2bf(o0), f2bf(o1), f2bf(o2), f2bf(o3));
      ((ushort4*)xk_bf)[(size_t)gn * 32 + d4] = ov;
    }
  }
}

// ---------------- Laplacian gather passes, bf16 feat, 4 edges/instr ----------
// PASS 1: feat=xk  -> xk1(bf16) = xk - dinv*sum ; hi(fp32,ws) = .5 xk + .3 xk1
// PASS 2: feat=xk1 -> xk2 = xk1 - dinv*sum; ahi(bf16) = hi + .2 xk2
template <int PASS>
__global__ __launch_bounds__(256)
void k_gather(const unsigned short* __restrict__ feat,
              unsigned short* __restrict__ feat_out,
              float* __restrict__ hi,
              unsigned short* __restrict__ ahi,
              const int* __restrict__ csr, const int* __restrict__ offs,
              const int* __restrict__ degs, const float* __restrict__ dinv) {
  int node = blockIdx.x * 4 + (threadIdx.x >> 6);
  int lane = threadIdx.x & 63;
  int quad = lane >> 4;
  int l16 = lane & 15;
  int start = offs[node];
  int cnt = degs[node];
  const uint4* f16 = (const uint4*)feat;   // one row = 16 uint4
  float acc[8];
  #pragma unroll
  for (int i = 0; i < 8; i++) acc[i] = 0.f;

  int j = 0;
  for (; j + 8 <= cnt; j += 8) {            // 8 edges in flight
    int sa = csr[start + j + quad];
    int sb = csr[start + j + 4 + quad];
    float da = dinv[sa], db = dinv[sb];
    uint4 va = f16[(size_t)sa * 16 + l16];
    uint4 vb = f16[(size_t)sb * 16 + l16];
    bfma8(acc, va, da);
    bfma8(acc, vb, db);
  }
  if (j + 4 <= cnt) {
    int s = csr[start + j + quad];
    float d = dinv[s];
    uint4 v = f16[(size_t)s * 16 + l16];
    bfma8(acc, v, d);
    j += 4;
  }
  int rem = cnt - j;                        // 0..3
  if (quad < rem) {
    int s = csr[start + j + quad];
    float d = dinv[s];
    uint4 v = f16[(size_t)s * 16 + l16];
    bfma8(acc, v, d);
  }

  #pragma unroll
  for (int i = 0; i < 8; i++) {
    acc[i] += __shfl_down(acc[i], 32);
    acc[i] += __shfl_down(acc[i], 16);
  }

  if (quad == 0) {
    float dvi = dinv[node];
    float old[8], nw[8];
    unpack8(old, f16[(size_t)node * 16 + l16]);
    #pragma unroll
    for (int i = 0; i < 8; i++) nw[i] = old[i] - acc[i] * dvi;
    if (PASS == 1) {
      ((uint4*)feat_out)[(size_t)node * 16 + l16] = pack8(nw);
      float h[8];
      #pragma unroll
      for (int i = 0; i < 8; i++) h[i] = 0.5f * old[i] + 0.3f * nw[i];
      float4* hp = (float4*)(hi + (size_t)node * 128 + l16 * 8);
      hp[0] = make_float4(h[0], h[1], h[2], h[3]);
      hp[1] = make_float4(h[4], h[5], h[6], h[7]);
    } else {
      const float4* hp = (const float4*)(hi + (size_t)node * 128 + l16 * 8);
      float4 a = hp[0], b = hp[1];
      float h[8] = {a.x, a.y, a.z, a.w, b.x, b.y, b.z, b.w};
      #pragma unroll
      for (int i = 0; i < 8; i++) h[i] += 0.2f * nw[i];
      ((uint4*)ahi)[(size_t)node * 16 + l16] = pack8(h);
    }
  }
}

// ---------------- precompute merged weights -> bf16 in b-fragment order ------
// Logical Wall[k][d], k in [0,384), d in [0,128):
//   k<128 : lin_w[d][k]
//   else  : sum_j weights[k-128][j] * lin_w[d][128+j]
// Emitted so that the wave's b-frag load for (kb, t) is contiguous:
//   wbtf[ ((kb*8 + t)*64 + lane)*8 + j ]  with lane=(quad*16+l16),
//   holding Wall[kb*32 + quad*8 + j][t*16 + l16].
__global__ void k_pre(const float* __restrict__ weights, const float* __restrict__ lin_w,
                      unsigned short* __restrict__ wbtf) {
  int gid = blockIdx.x * 256 + threadIdx.x;   // 384*128 threads
  int k = gid >> 7, d = gid & 127;
  float v;
  if (k < 128) {
    v = lin_w[d * 256 + k];
  } else {
    const float* wrow = weights + (k - 128) * 128;
    const float* lcol = lin_w + d * 256 + 128;
    float s = 0.f;
    for (int j = 0; j < 128; j++) s += wrow[j] * lcol[j];
    v = s;
  }
  int kb = k >> 5, kr = k & 31;
  int quad = kr >> 3, j = kr & 7;
  int t = d >> 4, l16 = d & 15;
  int lane = quad * 16 + l16;
  wbtf[(((kb * 8 + t) * 64 + lane) << 3) + j] = f2bf(v);
}

// ---------------- fused final GEMM via MFMA bf16 — no LDS, no barriers -------
// out = lrelu([ein | ahi | x] @ Wall + lin_b) + x0
// block: 4 independent waves x (16 rows x 128 cols); K=384 in 12 steps.
// B read as pre-swizzled frags: one coalesced dwordx4 per (kb,t), L1/L2-hot.
__global__ __launch_bounds__(256, 4)
void k_gemm2(const float* __restrict__ ein, const unsigned short* __restrict__ ahi,
             const float* __restrict__ x, const unsigned short* __restrict__ wbtf,
             const float* __restrict__ lin_b, const float* __restrict__ x0,
             float* __restrict__ out) {
  int tid = threadIdx.x;
  int lane = tid & 63, wv = tid >> 6;
  int quad = lane >> 4, l16 = lane & 15;
  int n0 = blockIdx.x * 64;
  int rA = n0 + wv * 16 + l16;
  if (rA >= N_NODES) rA = N_NODES - 1;      // clamped dup; store-guarded
  int kq = quad * 8;

  // ---- 12 a_frags in registers (A row = rA) ----
  short8 af[12];
  #pragma unroll
  for (int kb = 0; kb < 4; kb++) {          // cols 0-127: ein (fp32 -> bf16)
    const float4* p = (const float4*)(ein + (size_t)rA * 128 + kb * 32 + kq);
    float4 a = p[0], b = p[1];
    short8 t;
    t[0] = (short)f2bf(a.x); t[1] = (short)f2bf(a.y);
    t[2] = (short)f2bf(a.z); t[3] = (short)f2bf(a.w);
    t[4] = (short)f2bf(b.x); t[5] = (short)f2bf(b.y);
    t[6] = (short)f2bf(b.z); t[7] = (short)f2bf(b.w);
    af[kb] = t;
  }
  #pragma unroll
  for (int kb = 0; kb < 4; kb++)            // cols 128-255: ahi (bf16)
    af[4 + kb] = *(const short8*)(ahi + (size_t)rA * 128 + kb * 32 + kq);
  #pragma unroll
  for (int kb = 0; kb < 4; kb++) {          // cols 256-383: x (fp32 -> bf16)
    const float4* p = (const float4*)(x + (size_t)rA * 128 + kb * 32 + kq);
    float4 a = p[0], b = p[1];
    short8 t;
    t[0] = (short)f2bf(a.x); t[1] = (short)f2bf(a.y);
    t[2] = (short)f2bf(a.z); t[3] = (short)f2bf(a.w);
    t[4] = (short)f2bf(b.x); t[5] = (short)f2bf(b.y);
    t[6] = (short)f2bf(b.z); t[7] = (short)f2bf(b.w);
    af[8 + kb] = t;
  }

  f32x4 acc[8];
  #pragma unroll
  for (int i = 0; i < 8; i++) acc[i] = (f32x4){0.f, 0.f, 0.f, 0.f};

  const short8* bf = (const short8*)wbtf;
  #pragma unroll
  for (int kb = 0; kb < 12; kb++) {
    short8 a = af[kb];
    #pragma unroll
    for (int t = 0; t < 8; t++) {
      short8 b = bf[(kb * 8 + t) * 64 + lane];   // coalesced, L1/L2-hot
      acc[t] = __builtin_amdgcn_mfma_f32_16x16x32_bf16(a, b, acc[t], 0, 0, 0);
    }
  }

  // ---- epilogue: +bias, lrelu, +x0 ----
  #pragma unroll
  for (int t = 0; t < 8; t++) {
    int col = t * 16 + l16;
    float bl = lin_b[col];
    #pragma unroll
    for (int r = 0; r < 4; r++) {
      int gn = n0 + wv * 16 + quad * 4 + r;
      if (gn < N_NODES) {
        float v = acc[t][r] + bl;
        v = (v > 0.f) ? v : 0.01f * v;
        out[(size_t)gn * 128 + col] = v + x0[(size_t)gn * 128 + col];
      }
    }
  }
}

extern "C" void kernel_launch(void* const* d_in, const int* in_sizes, int n_in,
                              void* d_out, int out_size, void* d_ws, size_t ws_size,
                              hipStream_t stream) {
  const int*   src     = (const int*)d_in[0];
  const int*   dst     = (const int*)d_in[1];
  const float* x0      = (const float*)d_in[2];
  const float* x       = (const float*)d_in[3];
  const float* ein     = (const float*)d_in[4];
  const float* alpha   = (const float*)d_in[7];
  const float* emb     = (const float*)d_in[8];
  const float* w1      = (const float*)d_in[9];
  const float* b1      = (const float*)d_in[10];
  const float* w2      = (const float*)d_in[11];
  const float* b2      = (const float*)d_in[12];
  const float* weights = (const float*)d_in[13];
  const float* lin_w   = (const float*)d_in[14];
  const float* lin_b   = (const float*)d_in[15];
  float* out = (float*)d_out;

  // workspace layout (~82 MB)
  unsigned short* xk_bf  = (unsigned short*)d_ws;             // N*128 bf16
  unsigned short* xk1_bf = xk_bf  + (size_t)N_NODES * 128;
  unsigned short* ahi    = xk1_bf + (size_t)N_NODES * 128;
  unsigned short* wbtf   = ahi    + (size_t)N_NODES * 128;    // 12*8*64*8 bf16 = 96 KB
  float* dinv = (float*)(wbtf + 12 * 8 * 64 * 8);
  int* degs   = (int*)(dinv + N_NODES);
  int* offs   = degs + N_NODES;
  int* cursor = offs + N_NODES;
  int* aux    = cursor + N_NODES;
  int* aux2   = aux + 512;
  int* csr    = aux2 + 512;

  hipMemsetAsync(degs, 0, sizeof(int) * 3 * (size_t)N_NODES, stream);

  int gE = (N_EDGES + 255) / 256;
  int gN = (N_NODES + 255) / 256;   // 391
  k_deg  <<<gE, 256, 0, stream>>>(dst, degs);
  k_scan1<<<gN, 256, 0, stream>>>(degs, offs, aux);
  k_scan2<<<1, 512, 0, stream>>>(aux, aux2, gN);
  k_scan3<<<gN, 256, 0, stream>>>(offs, aux2, degs, dinv);
  k_fill <<<gE, 256, 0, stream>>>(src, dst, offs, cursor, csr);

  k_mlp<<<(N_NODES + 63) / 64, 256, 0, stream>>>(x, w1, w2, b1, b2, emb, alpha, xk_bf);
  k_pre<<<192, 256, 0, stream>>>(weights, lin_w, wbtf);

  float* hi = out;   // fp32 hi lives in d_out between pass1 and gemm
  k_gather<1><<<N_NODES / 4, 256, 0, stream>>>(xk_bf,  xk1_bf, hi, nullptr, csr, offs, degs, dinv);
  k_gather<2><<<N_NODES / 4, 256, 0, stream>>>(xk1_bf, nullptr, hi, ahi,    csr, offs, degs, dinv);

  k_gemm2<<<(N_NODES + 63) / 64, 256, 0, stream>>>(ein, ahi, x, wbtf, lin_b, x0, out);
}